// Round 3
// baseline (581.104 us; speedup 1.0000x reference)
//
#include <hip/hip_runtime.h>
#include <stdint.h>

#define B_DIM 8
#define T_DIM 1024
#define C_DIM 2048
#define M_DIM (B_DIM * T_DIM)   // 8192 rows = B*T
#define SEG   32                // segments for wkv scan
#define SEGL  (T_DIM / SEG)     // 32 steps per segment

typedef __bf16 bf16x8 __attribute__((ext_vector_type(8)));
typedef __bf16 bf16x4 __attribute__((ext_vector_type(4)));
typedef float  f32x4  __attribute__((ext_vector_type(4)));

// ---------------------------------------------------------------------------
// Downcast the 4 weight matrices fp32 -> bf16.  grid (C*C/1024, 4) x 256.
// ---------------------------------------------------------------------------
__global__ __launch_bounds__(256) void cast_w_kernel(
    const float* __restrict__ w0, const float* __restrict__ w1,
    const float* __restrict__ w2, const float* __restrict__ w3,
    __bf16* __restrict__ dst) {
    const float* srcs[4] = {w0, w1, w2, w3};
    const float* s = srcs[blockIdx.y];
    __bf16* d = dst + (size_t)blockIdx.y * (size_t)C_DIM * C_DIM;
    const size_t i = ((size_t)blockIdx.x * 256 + threadIdx.x) * 4;
    f32x4 v = *(const f32x4*)(s + i);
    bf16x4 o;
#pragma unroll
    for (int j = 0; j < 4; ++j) o[j] = (__bf16)v[j];
    *(bf16x4*)(d + i) = o;
}

// ---------------------------------------------------------------------------
// Time-shift mixing: xk/xv/xr = x*m + shift(x)*(1-m).  fp32 in, bf16 out.
// ---------------------------------------------------------------------------
__global__ __launch_bounds__(256) void mix4_kernel(
    const float* __restrict__ x,
    const float* __restrict__ mk, const float* __restrict__ mv,
    const float* __restrict__ mr,
    __bf16* __restrict__ xk, __bf16* __restrict__ xv, __bf16* __restrict__ xr) {
    const size_t idx = ((size_t)blockIdx.x * 256 + threadIdx.x) * 4;
    const int c = (int)(idx & (C_DIM - 1));
    const int t = (int)((idx >> 11) & (T_DIM - 1));   // C_DIM == 2^11

    f32x4 xc = *(const f32x4*)(x + idx);
    f32x4 sh = {0.f, 0.f, 0.f, 0.f};
    if (t != 0) sh = *(const f32x4*)(x + idx - C_DIM);
    f32x4 k4 = *(const f32x4*)(mk + c);
    f32x4 v4 = *(const f32x4*)(mv + c);
    f32x4 r4 = *(const f32x4*)(mr + c);

    bf16x4 ok, ov, orr;
#pragma unroll
    for (int j = 0; j < 4; ++j) {
        float xx = xc[j], ss = sh[j];
        ok[j]  = (__bf16)(xx * k4[j] + ss * (1.f - k4[j]));
        ov[j]  = (__bf16)(xx * v4[j] + ss * (1.f - v4[j]));
        orr[j] = (__bf16)(xx * r4[j] + ss * (1.f - r4[j]));
    }
    *(bf16x4*)(xk + idx) = ok;
    *(bf16x4*)(xv + idx) = ov;
    *(bf16x4*)(xr + idx) = orr;
}

// ---------------------------------------------------------------------------
// 256x256 bf16 GEMM, B^T input:  Cout[m][n] = sum_k A[m][k] * W[n][k]
//
// R3: register-staged (T14), single 64-KB LDS buffer.  Diagnosis from R1/R2:
// two different schedules, identical 82 us and identical FETCH -> the
// global_load_lds DMA path's delivery (~10.7 B/cyc/CU, burst-then-drain,
// <=64 KB in flight) was the limiter, not the schedule.  Changes:
//   - Plain global_load_dwordx4 into a 2-set register ring, issued one full
//     supertile (64 K) ahead: in-flight stream is continuous and rides the
//     normal vector path (deep OOO), not the LDS-DMA engine.
//   - Global loads are LINEAR (coalesced 128-B rows); the XOR swizzle is
//     applied on the ds_write side (we control both sides now).
//     Write = 8-row full bank sweep (conflict-free); read pattern is the
//     R2-verified one (slot g^(row&7)) -> numerics identical.
//   - Compute core = R2's 4-phase in-wave pipeline (counted lgkmcnt,
//     setprio around 16-MFMA clusters), no staging inside compute.
//   - Tile boundary: barrier (all reads drained by ph4's lgkm(0)) ->
//     vmcnt(0) (covered by a whole compute phase, ~2500+ cyc) -> ds_write
//     next tile -> issue tile+2 loads -> lgkm(0) -> barrier -> preload.
//   - 32-KB dead LDS pad pins occupancy at exactly 1 block/CU so the
//     256-block grid cannot be packed 2-per-CU onto half the CUs.
// ---------------------------------------------------------------------------
#define LGKM(N)  do { asm volatile("s_waitcnt lgkmcnt(" #N ")" ::: "memory"); \
                      __builtin_amdgcn_sched_barrier(0); } while (0)
#define LGKM0()  do { asm volatile("s_waitcnt lgkmcnt(0)" ::: "memory"); \
                      __builtin_amdgcn_sched_barrier(0); } while (0)
#define VMCNT0() asm volatile("s_waitcnt vmcnt(0)" ::: "memory")
#define VMCNT8() asm volatile("s_waitcnt vmcnt(8)" ::: "memory")

#define MF1(mi, jj, AV, BV) \
    acc[mi][jj] = __builtin_amdgcn_mfma_f32_16x16x32_bf16(AV, BV, acc[mi][jj], 0, 0, 0)

#define MFMA16(MB, AA, BB)                                                        \
    __builtin_amdgcn_s_setprio(1);                                                \
    MF1(MB+0,0,AA[0],BB[0]); MF1(MB+0,1,AA[0],BB[1]);                             \
    MF1(MB+0,2,AA[0],BB[2]); MF1(MB+0,3,AA[0],BB[3]);                             \
    MF1(MB+1,0,AA[1],BB[0]); MF1(MB+1,1,AA[1],BB[1]);                             \
    MF1(MB+1,2,AA[1],BB[2]); MF1(MB+1,3,AA[1],BB[3]);                             \
    MF1(MB+2,0,AA[2],BB[0]); MF1(MB+2,1,AA[2],BB[1]);                             \
    MF1(MB+2,2,AA[2],BB[2]); MF1(MB+2,3,AA[2],BB[3]);                             \
    MF1(MB+3,0,AA[3],BB[0]); MF1(MB+3,1,AA[3],BB[1]);                             \
    MF1(MB+3,2,AA[3],BB[2]); MF1(MB+3,3,AA[3],BB[3]);                             \
    __builtin_amdgcn_s_setprio(0)

// issue one supertile's 8 plain 16-B loads into a register set (A 4, B 4).
#define ISSUE(T, SA, SB)                                                          \
    do { const __bf16* ap_ = Ag + (size_t)(T) * 64;                               \
         const __bf16* bp_ = Bg + (size_t)(T) * 64;                               \
         SA[0] = *(const bf16x8*)(ap_);                                           \
         SA[1] = *(const bf16x8*)(ap_ + (size_t)64  * C_DIM);                     \
         SA[2] = *(const bf16x8*)(ap_ + (size_t)128 * C_DIM);                     \
         SA[3] = *(const bf16x8*)(ap_ + (size_t)192 * C_DIM);                     \
         SB[0] = *(const bf16x8*)(bp_);                                           \
         SB[1] = *(const bf16x8*)(bp_ + (size_t)64  * C_DIM);                     \
         SB[2] = *(const bf16x8*)(bp_ + (size_t)128 * C_DIM);                     \
         SB[3] = *(const bf16x8*)(bp_ + (size_t)192 * C_DIM); } while (0)

// swizzled ds_write of a staged supertile (rows +64 keep row&7 -> same slot).
#define DSWRITE(SA, SB)                                                           \
    do { *(bf16x8*)(sA + wbase)         = SA[0];                                  \
         *(bf16x8*)(sA + wbase + 4096)  = SA[1];                                  \
         *(bf16x8*)(sA + wbase + 8192)  = SA[2];                                  \
         *(bf16x8*)(sA + wbase + 12288) = SA[3];                                  \
         *(bf16x8*)(sB + wbase)         = SB[0];                                  \
         *(bf16x8*)(sB + wbase + 4096)  = SB[1];                                  \
         *(bf16x8*)(sB + wbase + 8192)  = SB[2];                                  \
         *(bf16x8*)(sB + wbase + 12288) = SB[3]; } while (0)

#define PRELOAD()                                                                 \
    do { a0[0]  = *(const bf16x8*)(sA + aE0);                                     \
         a0[1]  = *(const bf16x8*)(sA + aE0 + 1024);                              \
         a0[2]  = *(const bf16x8*)(sA + aE0 + 2048);                              \
         a0[3]  = *(const bf16x8*)(sA + aE0 + 3072);                              \
         b0f[0] = *(const bf16x8*)(sB + bE0);                                     \
         b0f[1] = *(const bf16x8*)(sB + bE0 + 1024);                              \
         b0f[2] = *(const bf16x8*)(sB + bE0 + 2048);                              \
         b0f[3] = *(const bf16x8*)(sB + bE0 + 3072); } while (0)

// 4 phases x 16 MFMA; each phase issues next phase's ds_reads, counted lgkm.
#define COMPUTE4()                                                                \
    do {                                                                          \
        a1[0] = *(const bf16x8*)(sA + aE0 + 4096);                                \
        a1[1] = *(const bf16x8*)(sA + aE0 + 5120);                                \
        a1[2] = *(const bf16x8*)(sA + aE0 + 6144);                                \
        a1[3] = *(const bf16x8*)(sA + aE0 + 7168);                                \
        LGKM(4);                                                                  \
        MFMA16(0, a0, b0f);                                                       \
        a0[0]  = *(const bf16x8*)(sA + aE1);                                      \
        a0[1]  = *(const bf16x8*)(sA + aE1 + 1024);                               \
        a0[2]  = *(const bf16x8*)(sA + aE1 + 2048);                               \
        a0[3]  = *(const bf16x8*)(sA + aE1 + 3072);                               \
        b1f[0] = *(const bf16x8*)(sB + bE1);                                      \
        b1f[1] = *(const bf16x8*)(sB + bE1 + 1024);                               \
        b1f[2] = *(const bf16x8*)(sB + bE1 + 2048);                               \
        b1f[3] = *(const bf16x8*)(sB + bE1 + 3072);                               \
        LGKM(8);                                                                  \
        MFMA16(4, a1, b0f);                                                       \
        a1[0] = *(const bf16x8*)(sA + aE1 + 4096);                                \
        a1[1] = *(const bf16x8*)(sA + aE1 + 5120);                                \
        a1[2] = *(const bf16x8*)(sA + aE1 + 6144);                                \
        a1[3] = *(const bf16x8*)(sA + aE1 + 7168);                                \
        LGKM(4);                                                                  \
        MFMA16(0, a0, b1f);                                                       \
        LGKM0();                                                                  \
        MFMA16(4, a1, b1f);                                                       \
    } while (0)

template <bool OUTF32>
__global__ __launch_bounds__(512, 2) void gemm256_bt(
    const __bf16* __restrict__ A, const __bf16* __restrict__ W,
    void* __restrict__ Cout) {
    __shared__ __align__(16) __bf16 sA[16384];   // 32 KB: [256][64] swizzled
    __shared__ __align__(16) __bf16 sB[16384];   // 32 KB
    __shared__ __align__(16) __bf16 pad[16384];  // 32 KB dead: pins 1 block/CU

    const int tid  = threadIdx.x;
    const int lane = tid & 63;
    const int wave = tid >> 6;
    const int wr   = wave >> 2;        // 0..1 -> m offset wr*128
    const int wc   = wave & 3;         // 0..3 -> n offset wc*64

    if (blockIdx.x == 0xFFFFFFFFu) pad[0] = (__bf16)0.f;  // keep pad live

    // XCD swizzle (unchanged; measured fine).
    const int bid = blockIdx.x;
    const int wid = (bid & 7) * 32 + (bid >> 3);
    const int m_blk = wid & 31;        // M_DIM/256 == 32
    const int n_blk = wid >> 5;        // C_DIM/256 == 8
    const int row0 = m_blk * 256;
    const int col0 = n_blk * 256;

    // Linear global staging addresses: thread covers rows (tid>>3)+64i,
    // k-group tid&7 (16 B).  8 threads = one contiguous 128-B row chunk.
    const int srow = tid >> 3;
    const int sg   = tid & 7;
    const __bf16* Ag = A + (size_t)(row0 + srow) * C_DIM + sg * 8;
    const __bf16* Bg = W + (size_t)(col0 + srow) * C_DIM + sg * 8;
    // ds_write base: row srow holds k-group sg at slot sg^(srow&7).
    const int wbase = srow * 64 + ((sg ^ (srow & 7)) * 8);

    // Fragment read bases (R2-verified): lane (row=R0+l15, q=lane>>4) reads
    // k-group g=4*ks+q at slot g^(l15&7); ks=1 flips slot bit2 -> XOR 32.
    const int l15 = lane & 15;
    const int q   = lane >> 4;
    const int sw0 = (q ^ (l15 & 7)) * 8;
    const int aE0 = wr * 8192 + l15 * 64 + sw0;
    const int aE1 = aE0 ^ 32;
    const int bE0 = wc * 4096 + l15 * 64 + sw0;
    const int bE1 = bE0 ^ 32;

    f32x4  acc[8][4] = {};
    bf16x8 a0[4], a1[4], b0f[4], b1f[4];
    bf16x8 S0A[4], S0B[4], S1A[4], S1B[4];   // 2-set register staging ring

    // ---- prologue: issue tiles 0,1; commit tile 0 to LDS; preload ph1.
    ISSUE(0, S0A, S0B);
    ISSUE(1, S1A, S1B);
    VMCNT8();                    // tile 0 landed (tile 1 stays in flight)
    DSWRITE(S0A, S0B);
    LGKM0();
    __builtin_amdgcn_s_barrier();
    PRELOAD();

    // ---- main: 15 pairs cover supertiles 0..29; 30,31 peeled.
#pragma unroll 1
    for (int p = 0; p < 15; ++p) {
        const int s = 2 * p;
        COMPUTE4();                      // tile s (reads drained by ph4 lgkm0)
        __builtin_amdgcn_s_barrier();    // all waves done reading LDS
        VMCNT0();                        // tile s+1 regs landed (1 tile cover)
        DSWRITE(S1A, S1B);               // tile s+1 -> LDS
        ISSUE(s + 2, S0A, S0B);          // refill freed set, 1 tile ahead
        LGKM0();
        __builtin_amdgcn_s_barrier();
        PRELOAD();

        COMPUTE4();                      // tile s+1
        __builtin_amdgcn_s_barrier();
        VMCNT0();
        DSWRITE(S0A, S0B);               // tile s+2 -> LDS
        ISSUE(s + 3, S1A, S1B);
        LGKM0();
        __builtin_amdgcn_s_barrier();
        PRELOAD();
    }
    // s = 30
    COMPUTE4();
    __builtin_amdgcn_s_barrier();
    VMCNT0();
    DSWRITE(S1A, S1B);                   // tile 31 -> LDS
    LGKM0();
    __builtin_amdgcn_s_barrier();
    PRELOAD();
    // s = 31
    COMPUTE4();

    // Epilogue: D row = (lane>>4)*4 + reg, col = lane&15 (m89-verified).
    const int crow = (lane >> 4) * 4;
#pragma unroll
    for (int mf = 0; mf < 8; ++mf)
#pragma unroll
        for (int jf = 0; jf < 4; ++jf)
#pragma unroll
            for (int r = 0; r < 4; ++r) {
                const int row = row0 + wr * 128 + mf * 16 + crow + r;
                const int col = col0 + wc * 64 + jf * 16 + l15;
                if constexpr (OUTF32) {
                    ((float*)Cout)[(size_t)row * C_DIM + col] = acc[mf][jf][r];
                } else {
                    ((__bf16*)Cout)[(size_t)row * C_DIM + col] = (__bf16)acc[mf][jf][r];
                }
            }
}

// ---------------------------------------------------------------------------
// WKV segmented scan.  State (num, den, mx): stabilized linear recurrence.
// pass1: per (b,c,seg) compute segment aggregate from zero state.
// pass2: per (b,c) sequentially combine aggregates -> incoming state per seg.
// pass3: per (b,c,seg) replay segment from incoming state, emit gated output.
// State layout: [seg][b][c] fp32, coalesced over c.
// ---------------------------------------------------------------------------
__global__ __launch_bounds__(256) void wkv_pass1(
    const __bf16* __restrict__ kbuf, const __bf16* __restrict__ vbuf,
    const float* __restrict__ td,
    float* __restrict__ st_num, float* __restrict__ st_den,
    float* __restrict__ st_m) {
    const int c = blockIdx.x * 256 + threadIdx.x;
    const int b = blockIdx.y;
    const int s = blockIdx.z;
    const size_t base = (size_t)b * T_DIM * C_DIM + (size_t)s * SEGL * C_DIM + c;

    const float w = -__expf(td[c]);
    float num = 0.f, den = 0.f, mx = -1e38f;

    for (int t0 = 0; t0 < SEGL; t0 += 8) {
        float kt[8], vt[8];
#pragma unroll
        for (int j = 0; j < 8; ++j) {
            const size_t idx = base + (size_t)(t0 + j) * C_DIM;
            kt[j] = (float)kbuf[idx];
            vt[j] = (float)vbuf[idx];
        }
#pragma unroll
        for (int j = 0; j < 8; ++j) {
            float ms  = fmaxf(mx + w, kt[j]);
            float e1s = __expf(mx + w - ms);
            float e2s = __expf(kt[j] - ms);
            num = e1s * num + e2s * vt[j];
            den = e1s * den + e2s;
            mx  = ms;
        }
    }
    const size_t sidx = (size_t)s * (B_DIM * C_DIM) + (size_t)b * C_DIM + c;
    st_num[sidx] = num;
    st_den[sidx] = den;
    st_m[sidx]   = mx;
}

__global__ __launch_bounds__(256) void wkv_pass2(
    const float* __restrict__ td,
    float* __restrict__ st_num, float* __restrict__ st_den,
    float* __restrict__ st_m) {
    const int bc = blockIdx.x * 256 + threadIdx.x;   // b*C + c
    const int c  = bc & (C_DIM - 1);
    const float w = -__expf(td[c]);
    const float wL = w * SEGL;

    float num = 0.f, den = 0.f, mx = -1e38f;
    for (int s = 0; s < SEG; ++s) {
        const size_t sidx = (size_t)s * (B_DIM * C_DIM) + bc;
        float na = st_num[sidx], da = st_den[sidx], ma = st_m[sidx];
        // write incoming state for this segment (overwrite aggregate)
        st_num[sidx] = num; st_den[sidx] = den; st_m[sidx] = mx;
        // combine: state <- decay^L(state) + aggregate
        float md = mx + wL;
        float mc = fmaxf(md, ma);
        float e1 = __expf(md - mc);
        float e2 = __expf(ma - mc);
        num = e1 * num + e2 * na;
        den = e1 * den + e2 * da;
        mx  = mc;
    }
}

__global__ __launch_bounds__(256) void wkv_pass3(
    const __bf16* __restrict__ kbuf, const __bf16* __restrict__ vbuf,
    const __bf16* __restrict__ rbuf, const float* __restrict__ td,
    const float* __restrict__ tf,
    const float* __restrict__ st_num, const float* __restrict__ st_den,
    const float* __restrict__ st_m, __bf16* __restrict__ abuf) {
    const int c = blockIdx.x * 256 + threadIdx.x;
    const int b = blockIdx.y;
    const int s = blockIdx.z;
    const size_t base = (size_t)b * T_DIM * C_DIM + (size_t)s * SEGL * C_DIM + c;

    const float w = -__expf(td[c]);
    const float u = tf[c];
    const size_t sidx = (size_t)s * (B_DIM * C_DIM) + (size_t)b * C_DIM + c;
    float num = st_num[sidx], den = st_den[sidx], mx = st_m[sidx];

    for (int t0 = 0; t0 < SEGL; t0 += 8) {
        float kt[8], vt[8], rt[8];
#pragma unroll
        for (int j = 0; j < 8; ++j) {
            const size_t idx = base + (size_t)(t0 + j) * C_DIM;
            kt[j] = (float)kbuf[idx];
            vt[j] = (float)vbuf[idx];
            rt[j] = (float)rbuf[idx];
        }
#pragma unroll
        for (int j = 0; j < 8; ++j) {
            float mo  = fmaxf(mx, kt[j] + u);
            float e1  = __expf(mx - mo);
            float e2  = __expf(kt[j] + u - mo);
            float out = (e1 * num + e2 * vt[j]) / (e1 * den + e2);

            float ms  = fmaxf(mx + w, kt[j]);
            float e1s = __expf(mx + w - ms);
            float e2s = __expf(kt[j] - ms);
            num = e1s * num + e2s * vt[j];
            den = e1s * den + e2s;
            mx  = ms;

            float sr = 1.f / (1.f + __expf(-rt[j]));
            abuf[base + (size_t)(t0 + j) * C_DIM] = (__bf16)(sr * out);
        }
    }
}

// ---------------------------------------------------------------------------
extern "C" void kernel_launch(void* const* d_in, const int* in_sizes, int n_in,
                              void* d_out, int out_size, void* d_ws, size_t ws_size,
                              hipStream_t stream) {
    (void)in_sizes; (void)n_in; (void)out_size; (void)ws_size;
    const float* x  = (const float*)d_in[0];
    const float* td = (const float*)d_in[1];
    const float* tf = (const float*)d_in[2];
    const float* mk = (const float*)d_in[3];
    const float* mv = (const float*)d_in[4];
    const float* mr = (const float*)d_in[5];
    const float* Wk = (const float*)d_in[6];
    const float* Wv = (const float*)d_in[7];
    const float* Wr = (const float*)d_in[8];
    const float* Wo = (const float*)d_in[9];
    float* out = (float*)d_out;

    const size_t WN = (size_t)C_DIM * C_DIM;    // 4,194,304
    const size_t n  = (size_t)M_DIM * C_DIM;    // 16,777,216

    // ws layout (bf16 elements): [Wk|Wv|Wr|Wo bf16][slot0][slot1][slot2][slot3]
    __bf16* Wb  = (__bf16*)d_ws;
    __bf16* Wkb = Wb;
    __bf16* Wvb = Wb + WN;
    __bf16* Wrb = Wb + 2 * WN;
    __bf16* Wob = Wb + 3 * WN;
    __bf16* xk  = Wb + 4 * WN;                  // slot 0
    __bf16* xv  = xk + n;                       // slot 1
    __bf16* xr  = xv + n;                       // slot 2
    __bf16* kb  = xr + n;                       // slot 3
    __bf16* vb  = xk;                           // reuse slot 0 (xk dead)
    __bf16* rb  = xv;                           // reuse slot 1 (xv dead)
    __bf16* ab  = xr;                           // reuse slot 2 (xr dead)

    // WKV state arrays (6.3 MB) live in the Wkb region: Wkb is dead once the
    // k-GEMM completes, and cast_w rewrites it at the start of every launch.
    float* st_num = (float*)d_ws;
    float* st_den = st_num + (size_t)SEG * B_DIM * C_DIM;
    float* st_m   = st_den + (size_t)SEG * B_DIM * C_DIM;

    cast_w_kernel<<<dim3((unsigned)(WN / 4 / 256), 4), 256, 0, stream>>>(
        Wk, Wv, Wr, Wo, Wb);

    mix4_kernel<<<dim3((unsigned)(n / 4 / 256)), 256, 0, stream>>>(
        x, mk, mv, mr, xk, xv, xr);

    dim3 ggrid((M_DIM / 256) * (C_DIM / 256));  // 32 x 8 = 256 blocks (1/CU)
    gemm256_bt<false><<<ggrid, 512, 0, stream>>>(xk, Wkb, kb);
    gemm256_bt<false><<<ggrid, 512, 0, stream>>>(xv, Wvb, vb);
    gemm256_bt<false><<<ggrid, 512, 0, stream>>>(xr, Wrb, rb);

    dim3 wgrid(C_DIM / 256, B_DIM, SEG);        // 8 x 8 x 32 = 2048 blocks
    wkv_pass1<<<wgrid, 256, 0, stream>>>(kb, vb, td, st_num, st_den, st_m);
    wkv_pass2<<<dim3(B_DIM * C_DIM / 256), 256, 0, stream>>>(
        td, st_num, st_den, st_m);
    wkv_pass3<<<wgrid, 256, 0, stream>>>(kb, vb, rb, td, tf,
                                         st_num, st_den, st_m, ab);

    gemm256_bt<true><<<ggrid, 512, 0, stream>>>(ab, Wob, out);
}

// Round 4
// 500.468 us; speedup vs baseline: 1.1611x; 1.1611x over previous
//
#include <hip/hip_runtime.h>
#include <stdint.h>

#define B_DIM 8
#define T_DIM 1024
#define C_DIM 2048
#define M_DIM (B_DIM * T_DIM)   // 8192 rows = B*T
#define SEG   32                // segments for wkv scan
#define SEGL  (T_DIM / SEG)     // 32 steps per segment

typedef __bf16 bf16x8 __attribute__((ext_vector_type(8)));
typedef __bf16 bf16x4 __attribute__((ext_vector_type(4)));
typedef float  f32x4  __attribute__((ext_vector_type(4)));

// ---------------------------------------------------------------------------
// async global -> LDS, 16 bytes per lane (global_load_lds_dwordx4).
// LDS dest is wave-uniform base + lane*16 (m104/m108 semantics).
// ---------------------------------------------------------------------------
__device__ __forceinline__ void gld_lds16(const void* g, void* l) {
    __builtin_amdgcn_global_load_lds((__attribute__((address_space(1))) void*)g,
                                     (__attribute__((address_space(3))) void*)l,
                                     16, 0, 0);
}

// ---------------------------------------------------------------------------
// Downcast the 4 weight matrices fp32 -> bf16.  grid (C*C/1024, 4) x 256.
// ---------------------------------------------------------------------------
__global__ __launch_bounds__(256) void cast_w_kernel(
    const float* __restrict__ w0, const float* __restrict__ w1,
    const float* __restrict__ w2, const float* __restrict__ w3,
    __bf16* __restrict__ dst) {
    const float* srcs[4] = {w0, w1, w2, w3};
    const float* s = srcs[blockIdx.y];
    __bf16* d = dst + (size_t)blockIdx.y * (size_t)C_DIM * C_DIM;
    const size_t i = ((size_t)blockIdx.x * 256 + threadIdx.x) * 4;
    f32x4 v = *(const f32x4*)(s + i);
    bf16x4 o;
#pragma unroll
    for (int j = 0; j < 4; ++j) o[j] = (__bf16)v[j];
    *(bf16x4*)(d + i) = o;
}

// ---------------------------------------------------------------------------
// Time-shift mixing: xk/xv/xr = x*m + shift(x)*(1-m).  fp32 in, bf16 out.
// ---------------------------------------------------------------------------
__global__ __launch_bounds__(256) void mix4_kernel(
    const float* __restrict__ x,
    const float* __restrict__ mk, const float* __restrict__ mv,
    const float* __restrict__ mr,
    __bf16* __restrict__ xk, __bf16* __restrict__ xv, __bf16* __restrict__ xr) {
    const size_t idx = ((size_t)blockIdx.x * 256 + threadIdx.x) * 4;
    const int c = (int)(idx & (C_DIM - 1));
    const int t = (int)((idx >> 11) & (T_DIM - 1));   // C_DIM == 2^11

    f32x4 xc = *(const f32x4*)(x + idx);
    f32x4 sh = {0.f, 0.f, 0.f, 0.f};
    if (t != 0) sh = *(const f32x4*)(x + idx - C_DIM);
    f32x4 k4 = *(const f32x4*)(mk + c);
    f32x4 v4 = *(const f32x4*)(mv + c);
    f32x4 r4 = *(const f32x4*)(mr + c);

    bf16x4 ok, ov, orr;
#pragma unroll
    for (int j = 0; j < 4; ++j) {
        float xx = xc[j], ss = sh[j];
        ok[j]  = (__bf16)(xx * k4[j] + ss * (1.f - k4[j]));
        ov[j]  = (__bf16)(xx * v4[j] + ss * (1.f - v4[j]));
        orr[j] = (__bf16)(xx * r4[j] + ss * (1.f - r4[j]));
    }
    *(bf16x4*)(xk + idx) = ok;
    *(bf16x4*)(xv + idx) = ov;
    *(bf16x4*)(xr + idx) = orr;
}

// ---------------------------------------------------------------------------
// 256x256 bf16 GEMM, B^T input:  Cout[m][n] = sum_k A[m][k] * W[n][k]
//
// R4: faithful port of the m201 8-phase schedule (1563 TF @4k on this chip),
// adapted to K-HALF staging (each wave reads its whole row-half every phase,
// so stage granularity must be k-halves, not row-halves).
//
//   LDS: 2 bufs x 2 k-halves x [256 rows][32 k] per matrix = 128 KiB total.
//   Per K-tile t (buf db = t&1), 4 phases (quadrant = ks x mh), each phase:
//     { ds_read subtile (8 or 4 x ds_read_b128);
//       stage ONE k-half (2 x global_load_lds);
//       sched_barrier; s_barrier; lgkmcnt(0)+sched_barrier;
//       setprio(1); 16 MFMA; setprio(0); s_barrier }
//   Stage stream (fixed ring, verified):   P1: t+1 A-kh1 -> buf db^1
//     P2: t+2 B-kh0 -> buf db   (region last read at P1, covered by barrier)
//     P3: t+2 A-kh0 -> buf db   (last read P2)
//     P4: t+2 B-kh1 -> buf db   (last read P3), then s_waitcnt vmcnt(6):
//   leaves exactly the 3 staged halves of t+2 (6 loads) in flight and
//   guarantees ALL of t+1 landed -- never drains to 0 in steady state.
//   Prologue stages 7 halves (t0 all, t1 B0/A0/B1) + vmcnt(6); tail peels
//   t=30 (stage t31 A-kh1 only, vmcnt(0)) and t=31 (no stage).
//
//   Swizzle (within each 64-B half-row, 4 slots of 16 B):
//     slot = kg ^ (row&3) ^ ((row>>2)&3)
//   -> per 16-lane ds_read_b128 batch each slot hit exactly 2x (free, m136).
//   Inverse applied on the DMA's GLOBAL source; LDS writes stay linear.
//   Fragment MFMA layout + epilogue = R1-R3 verified mapping (unchanged).
// ---------------------------------------------------------------------------
#define LGKM0()  do { asm volatile("s_waitcnt lgkmcnt(0)" ::: "memory"); \
                      __builtin_amdgcn_sched_barrier(0); } while (0)
#define VMC(N)   asm volatile("s_waitcnt vmcnt(" #N ")" ::: "memory")

#define MF1(mi, jj, AV, BV) \
    acc[mi][jj] = __builtin_amdgcn_mfma_f32_16x16x32_bf16(AV, BV, acc[mi][jj], 0, 0, 0)

#define MFQ(MB)                                                              \
    __builtin_amdgcn_s_setprio(1);                                           \
    MF1(MB+0,0,aF[0],bF[0]); MF1(MB+0,1,aF[0],bF[1]);                        \
    MF1(MB+0,2,aF[0],bF[2]); MF1(MB+0,3,aF[0],bF[3]);                        \
    MF1(MB+1,0,aF[1],bF[0]); MF1(MB+1,1,aF[1],bF[1]);                        \
    MF1(MB+1,2,aF[1],bF[2]); MF1(MB+1,3,aF[1],bF[3]);                        \
    MF1(MB+2,0,aF[2],bF[0]); MF1(MB+2,1,aF[2],bF[1]);                        \
    MF1(MB+2,2,aF[2],bF[2]); MF1(MB+2,3,aF[2],bF[3]);                        \
    MF1(MB+3,0,aF[3],bF[0]); MF1(MB+3,1,aF[3],bF[1]);                        \
    MF1(MB+3,2,aF[3],bF[2]); MF1(MB+3,3,aF[3],bF[3]);                        \
    __builtin_amdgcn_s_setprio(0)

// reads: A frags (4) for k-sub KS, m-half MH of this wave; B frags (4) for KS.
#define RD_A4(DB, KS, MH)                                                    \
    aF[0] = *(const bf16x8*)(sA + ((DB)*2+(KS))*8192 + wrA + ((MH)*4+0)*512 + rdOf); \
    aF[1] = *(const bf16x8*)(sA + ((DB)*2+(KS))*8192 + wrA + ((MH)*4+1)*512 + rdOf); \
    aF[2] = *(const bf16x8*)(sA + ((DB)*2+(KS))*8192 + wrA + ((MH)*4+2)*512 + rdOf); \
    aF[3] = *(const bf16x8*)(sA + ((DB)*2+(KS))*8192 + wrA + ((MH)*4+3)*512 + rdOf)

#define RD_B4(DB, KS)                                                        \
    bF[0] = *(const bf16x8*)(sB + ((DB)*2+(KS))*8192 + wcB + 0*512 + rdOf);  \
    bF[1] = *(const bf16x8*)(sB + ((DB)*2+(KS))*8192 + wcB + 1*512 + rdOf);  \
    bF[2] = *(const bf16x8*)(sB + ((DB)*2+(KS))*8192 + wcB + 2*512 + rdOf);  \
    bF[3] = *(const bf16x8*)(sB + ((DB)*2+(KS))*8192 + wcB + 3*512 + rdOf)

// stage k-half KH of tile T into buf DBX (2 loads: rows 0-127, 128-255).
#define STG_A(T, KH, DBX)                                                    \
    gld_lds16(AgS + (size_t)(T)*64 + (KH)*32,                                \
              sA + (DBX)*16384 + (KH)*8192 + wvOf);                          \
    gld_lds16(AgS + (size_t)(T)*64 + (KH)*32 + (size_t)128*C_DIM,            \
              sA + (DBX)*16384 + (KH)*8192 + 4096 + wvOf)
#define STG_B(T, KH, DBX)                                                    \
    gld_lds16(BgS + (size_t)(T)*64 + (KH)*32,                                \
              sB + (DBX)*16384 + (KH)*8192 + wvOf);                          \
    gld_lds16(BgS + (size_t)(T)*64 + (KH)*32 + (size_t)128*C_DIM,            \
              sB + (DBX)*16384 + (KH)*8192 + 4096 + wvOf)

#define KTILE(DB, S1, S2, S3, S4, VM4)                                       \
  {                                                                          \
    RD_B4(DB,0); RD_A4(DB,0,0); S1;                                          \
    __builtin_amdgcn_sched_barrier(0);                                       \
    __builtin_amdgcn_s_barrier(); LGKM0();                                   \
    MFQ(0);                                                                  \
    __builtin_amdgcn_s_barrier();                                            \
    RD_A4(DB,0,1); S2;                                                       \
    __builtin_amdgcn_sched_barrier(0);                                       \
    __builtin_amdgcn_s_barrier(); LGKM0();                                   \
    MFQ(4);                                                                  \
    __builtin_amdgcn_s_barrier();                                            \
    RD_B4(DB,1); RD_A4(DB,1,0); S3;                                          \
    __builtin_amdgcn_sched_barrier(0);                                       \
    __builtin_amdgcn_s_barrier(); LGKM0();                                   \
    MFQ(0);                                                                  \
    __builtin_amdgcn_s_barrier();                                            \
    RD_A4(DB,1,1); S4; VM4;                                                  \
    __builtin_amdgcn_sched_barrier(0);                                       \
    __builtin_amdgcn_s_barrier(); LGKM0();                                   \
    MFQ(4);                                                                  \
    __builtin_amdgcn_s_barrier();                                            \
  }

template <bool OUTF32>
__global__ __launch_bounds__(512, 2) void gemm256_bt(
    const __bf16* __restrict__ A, const __bf16* __restrict__ W,
    void* __restrict__ Cout) {
    // [buf][khalf][row 256][k 32] per matrix; 64 KB each, 128 KB total.
    __shared__ __align__(16) __bf16 sA[32768];
    __shared__ __align__(16) __bf16 sB[32768];

    const int tid  = threadIdx.x;
    const int lane = tid & 63;
    const int wave = tid >> 6;
    const int wr   = wave >> 2;        // 0..1 -> m offset wr*128
    const int wc   = wave & 3;         // 0..3 -> n offset wc*64

    // XCD swizzle: each XCD owns one n-panel (1MB W, L2-resident) x 32 m-blocks.
    const int bid = blockIdx.x;
    const int wid = (bid & 7) * 32 + (bid >> 3);
    const int m_blk = wid & 31;        // M_DIM/256 == 32
    const int n_blk = wid >> 5;        // C_DIM/256 == 8
    const int row0 = m_blk * 256;
    const int col0 = n_blk * 256;

    // Staging source.  Thread covers row srow (tid>>2), 16-B slot tid&3 of a
    // 64-B half-row; slot holds k-group kg = slot ^ (srow&3) ^ ((srow>>2)&3)
    // (inverse swizzle on global side; DMA LDS writes linear).
    const int srow = tid >> 2;                     // 0..127
    const int swkg = (tid & 3) ^ (srow & 3) ^ ((srow >> 2) & 3);
    const __bf16* AgS = A + (size_t)(row0 + srow) * C_DIM + swkg * 8;
    const __bf16* BgS = W + (size_t)(col0 + srow) * C_DIM + swkg * 8;
    const int wvOf = wave * 512;                   // per-wave DMA base (elems)

    // Fragment read base: lane (row=R0+l15, kg=q) -> slot q^(l15&3)^((l15>>2)&3)
    // (row bits above l15 are multiples of 16 -> swizzle is frag-invariant).
    const int l15 = lane & 15;
    const int q   = lane >> 4;
    const int rdOf = l15 * 32 + ((q ^ (l15 & 3) ^ ((l15 >> 2) & 3)) * 8);
    const int wrA  = wr * 4096;        // + mf*512 within region
    const int wcB  = wc * 2048;        // + nf*512 within region

    f32x4  acc[8][4] = {};
    bf16x8 aF[4], bF[4];

    // ---- prologue: t0 {A0,B0,A1,B1}, t1 {B0,A0,B1} = 14 loads; vmcnt(6)
    // drains all of t0, leaves t1's 3 halves in flight (steady-state entry).
    STG_A(0, 0, 0); STG_B(0, 0, 0); STG_A(0, 1, 0); STG_B(0, 1, 0);
    STG_B(1, 0, 1); STG_A(1, 0, 1); STG_B(1, 1, 1);
    VMC(6);
    __builtin_amdgcn_sched_barrier(0);
    __builtin_amdgcn_s_barrier();

    // ---- main: tiles 0..29 as 15 pairs; 30,31 peeled.
#pragma unroll 1
    for (int p = 0; p < 15; ++p) {
        const int t = 2 * p;
        KTILE(0, STG_A(t + 1, 1, 1), STG_B(t + 2, 0, 0),
                 STG_A(t + 2, 0, 0), STG_B(t + 2, 1, 0), VMC(6));
        KTILE(1, STG_A(t + 2, 1, 0), STG_B(t + 3, 0, 1),
                 STG_A(t + 3, 0, 1), STG_B(t + 3, 1, 1), VMC(6));
    }
    KTILE(0, STG_A(31, 1, 1), , , , VMC(0));   // t=30: finish t31, drain all
    KTILE(1, , , , , );                        // t=31: pure compute

    // Epilogue: D row = (lane>>4)*4 + reg, col = lane&15 (m89-verified).
    const int crow = (lane >> 4) * 4;
#pragma unroll
    for (int mf = 0; mf < 8; ++mf)
#pragma unroll
        for (int jf = 0; jf < 4; ++jf)
#pragma unroll
            for (int r = 0; r < 4; ++r) {
                const int row = row0 + wr * 128 + mf * 16 + crow + r;
                const int col = col0 + wc * 64 + jf * 16 + l15;
                if constexpr (OUTF32) {
                    ((float*)Cout)[(size_t)row * C_DIM + col] = acc[mf][jf][r];
                } else {
                    ((__bf16*)Cout)[(size_t)row * C_DIM + col] = (__bf16)acc[mf][jf][r];
                }
            }
}

// ---------------------------------------------------------------------------
// WKV segmented scan.  State (num, den, mx): stabilized linear recurrence.
// pass1: per (b,c,seg) compute segment aggregate from zero state.
// pass2: per (b,c) sequentially combine aggregates -> incoming state per seg.
// pass3: per (b,c,seg) replay segment from incoming state, emit gated output.
// State layout: [seg][b][c] fp32, coalesced over c.
// ---------------------------------------------------------------------------
__global__ __launch_bounds__(256) void wkv_pass1(
    const __bf16* __restrict__ kbuf, const __bf16* __restrict__ vbuf,
    const float* __restrict__ td,
    float* __restrict__ st_num, float* __restrict__ st_den,
    float* __restrict__ st_m) {
    const int c = blockIdx.x * 256 + threadIdx.x;
    const int b = blockIdx.y;
    const int s = blockIdx.z;
    const size_t base = (size_t)b * T_DIM * C_DIM + (size_t)s * SEGL * C_DIM + c;

    const float w = -__expf(td[c]);
    float num = 0.f, den = 0.f, mx = -1e38f;

    for (int t0 = 0; t0 < SEGL; t0 += 8) {
        float kt[8], vt[8];
#pragma unroll
        for (int j = 0; j < 8; ++j) {
            const size_t idx = base + (size_t)(t0 + j) * C_DIM;
            kt[j] = (float)kbuf[idx];
            vt[j] = (float)vbuf[idx];
        }
#pragma unroll
        for (int j = 0; j < 8; ++j) {
            float ms  = fmaxf(mx + w, kt[j]);
            float e1s = __expf(mx + w - ms);
            float e2s = __expf(kt[j] - ms);
            num = e1s * num + e2s * vt[j];
            den = e1s * den + e2s;
            mx  = ms;
        }
    }
    const size_t sidx = (size_t)s * (B_DIM * C_DIM) + (size_t)b * C_DIM + c;
    st_num[sidx] = num;
    st_den[sidx] = den;
    st_m[sidx]   = mx;
}

__global__ __launch_bounds__(256) void wkv_pass2(
    const float* __restrict__ td,
    float* __restrict__ st_num, float* __restrict__ st_den,
    float* __restrict__ st_m) {
    const int bc = blockIdx.x * 256 + threadIdx.x;   // b*C + c
    const int c  = bc & (C_DIM - 1);
    const float w = -__expf(td[c]);
    const float wL = w * SEGL;

    float num = 0.f, den = 0.f, mx = -1e38f;
    for (int s = 0; s < SEG; ++s) {
        const size_t sidx = (size_t)s * (B_DIM * C_DIM) + bc;
        float na = st_num[sidx], da = st_den[sidx], ma = st_m[sidx];
        // write incoming state for this segment (overwrite aggregate)
        st_num[sidx] = num; st_den[sidx] = den; st_m[sidx] = mx;
        // combine: state <- decay^L(state) + aggregate
        float md = mx + wL;
        float mc = fmaxf(md, ma);
        float e1 = __expf(md - mc);
        float e2 = __expf(ma - mc);
        num = e1 * num + e2 * na;
        den = e1 * den + e2 * da;
        mx  = mc;
    }
}

__global__ __launch_bounds__(256) void wkv_pass3(
    const __bf16* __restrict__ kbuf, const __bf16* __restrict__ vbuf,
    const __bf16* __restrict__ rbuf, const float* __restrict__ td,
    const float* __restrict__ tf,
    const float* __restrict__ st_num, const float* __restrict__ st_den,
    const float* __restrict__ st_m, __bf16* __restrict__ abuf) {
    const int c = blockIdx.x * 256 + threadIdx.x;
    const int b = blockIdx.y;
    const int s = blockIdx.z;
    const size_t base = (size_t)b * T_DIM * C_DIM + (size_t)s * SEGL * C_DIM + c;

    const float w = -__expf(td[c]);
    const float u = tf[c];
    const size_t sidx = (size_t)s * (B_DIM * C_DIM) + (size_t)b * C_DIM + c;
    float num = st_num[sidx], den = st_den[sidx], mx = st_m[sidx];

    for (int t0 = 0; t0 < SEGL; t0 += 8) {
        float kt[8], vt[8], rt[8];
#pragma unroll
        for (int j = 0; j < 8; ++j) {
            const size_t idx = base + (size_t)(t0 + j) * C_DIM;
            kt[j] = (float)kbuf[idx];
            vt[j] = (float)vbuf[idx];
            rt[j] = (float)rbuf[idx];
        }
#pragma unroll
        for (int j = 0; j < 8; ++j) {
            float mo  = fmaxf(mx, kt[j] + u);
            float e1  = __expf(mx - mo);
            float e2  = __expf(kt[j] + u - mo);
            float out = (e1 * num + e2 * vt[j]) / (e1 * den + e2);

            float ms  = fmaxf(mx + w, kt[j]);
            float e1s = __expf(mx + w - ms);
            float e2s = __expf(kt[j] - ms);
            num = e1s * num + e2s * vt[j];
            den = e1s * den + e2s;
            mx  = ms;

            float sr = 1.f / (1.f + __expf(-rt[j]));
            abuf[base + (size_t)(t0 + j) * C_DIM] = (__bf16)(sr * out);
        }
    }
}

// ---------------------------------------------------------------------------
extern "C" void kernel_launch(void* const* d_in, const int* in_sizes, int n_in,
                              void* d_out, int out_size, void* d_ws, size_t ws_size,
                              hipStream_t stream) {
    (void)in_sizes; (void)n_in; (void)out_size; (void)ws_size;
    const float* x  = (const float*)d_in[0];
    const float* td = (const float*)d_in[1];
    const float* tf = (const float*)d_in[2];
    const float* mk = (const float*)d_in[3];
    const float* mv = (const float*)d_in[4];
    const float* mr = (const float*)d_in[5];
    const float* Wk = (const float*)d_in[6];
    const float* Wv = (const float*)d_in[7];
    const float* Wr = (const float*)d_in[8];
    const float* Wo = (const float*)d_in[9];
    float* out = (float*)d_out;

    const size_t WN = (size_t)C_DIM * C_DIM;    // 4,194,304
    const size_t n  = (size_t)M_DIM * C_DIM;    // 16,777,216

    // ws layout (bf16 elements): [Wk|Wv|Wr|Wo bf16][slot0][slot1][slot2][slot3]
    __bf16* Wb  = (__bf16*)d_ws;
    __bf16* Wkb = Wb;
    __bf16* Wvb = Wb + WN;
    __bf16* Wrb = Wb + 2 * WN;
    __bf16* Wob = Wb + 3 * WN;
    __bf16* xk  = Wb + 4 * WN;                  // slot 0
    __bf16* xv  = xk + n;                       // slot 1
    __bf16* xr  = xv + n;                       // slot 2
    __bf16* kb  = xr + n;                       // slot 3
    __bf16* vb  = xk;                           // reuse slot 0 (xk dead)
    __bf16* rb  = xv;                           // reuse slot 1 (xv dead)
    __bf16* ab  = xr;                           // reuse slot 2 (xr dead)

    // WKV state arrays (6.3 MB) live in the Wkb region: Wkb is dead once the
    // k-GEMM completes, and cast_w rewrites it at the start of every launch.
    float* st_num = (float*)d_ws;
    float* st_den = st_num + (size_t)SEG * B_DIM * C_DIM;
    float* st_m   = st_den + (size_t)SEG * B_DIM * C_DIM;

    cast_w_kernel<<<dim3((unsigned)(WN / 4 / 256), 4), 256, 0, stream>>>(
        Wk, Wv, Wr, Wo, Wb);

    mix4_kernel<<<dim3((unsigned)(n / 4 / 256)), 256, 0, stream>>>(
        x, mk, mv, mr, xk, xv, xr);

    dim3 ggrid((M_DIM / 256) * (C_DIM / 256));  // 32 x 8 = 256 blocks (1/CU)
    gemm256_bt<false><<<ggrid, 512, 0, stream>>>(xk, Wkb, kb);
    gemm256_bt<false><<<ggrid, 512, 0, stream>>>(xv, Wvb, vb);
    gemm256_bt<false><<<ggrid, 512, 0, stream>>>(xr, Wrb, rb);

    dim3 wgrid(C_DIM / 256, B_DIM, SEG);        // 8 x 8 x 32 = 2048 blocks
    wkv_pass1<<<wgrid, 256, 0, stream>>>(kb, vb, td, st_num, st_den, st_m);
    wkv_pass2<<<dim3(B_DIM * C_DIM / 256), 256, 0, stream>>>(
        td, st_num, st_den, st_m);
    wkv_pass3<<<wgrid, 256, 0, stream>>>(kb, vb, rb, td, tf,
                                         st_num, st_den, st_m, ab);

    gemm256_bt<true><<<ggrid, 512, 0, stream>>>(ab, Wob, out);
}

// Round 5
// 488.174 us; speedup vs baseline: 1.1904x; 1.0252x over previous
//
#include <hip/hip_runtime.h>
#include <stdint.h>

#define B_DIM 8
#define T_DIM 1024
#define C_DIM 2048
#define M_DIM (B_DIM * T_DIM)   // 8192 rows = B*T
#define SEG   32                // segments for wkv scan
#define SEGL  (T_DIM / SEG)     // 32 steps per segment

typedef __bf16 bf16x8 __attribute__((ext_vector_type(8)));
typedef __bf16 bf16x4 __attribute__((ext_vector_type(4)));
typedef float  f32x4  __attribute__((ext_vector_type(4)));

// ---------------------------------------------------------------------------
// async global -> LDS, 16 bytes per lane (global_load_lds_dwordx4).
// ---------------------------------------------------------------------------
__device__ __forceinline__ void gld_lds16(const void* g, void* l) {
    __builtin_amdgcn_global_load_lds((__attribute__((address_space(1))) void*)g,
                                     (__attribute__((address_space(3))) void*)l,
                                     16, 0, 0);
}

// ---------------------------------------------------------------------------
// Downcast the 4 weight matrices fp32 -> bf16.  grid (C*C/1024, 4) x 256.
// ---------------------------------------------------------------------------
__global__ __launch_bounds__(256) void cast_w_kernel(
    const float* __restrict__ w0, const float* __restrict__ w1,
    const float* __restrict__ w2, const float* __restrict__ w3,
    __bf16* __restrict__ dst) {
    const float* srcs[4] = {w0, w1, w2, w3};
    const float* s = srcs[blockIdx.y];
    __bf16* d = dst + (size_t)blockIdx.y * (size_t)C_DIM * C_DIM;
    const size_t i = ((size_t)blockIdx.x * 256 + threadIdx.x) * 4;
    f32x4 v = *(const f32x4*)(s + i);
    bf16x4 o;
#pragma unroll
    for (int j = 0; j < 4; ++j) o[j] = (__bf16)v[j];
    *(bf16x4*)(d + i) = o;
}

// ---------------------------------------------------------------------------
// Time-shift mixing: xk/xv/xr = x*m + shift(x)*(1-m).  fp32 in, bf16 out.
// ---------------------------------------------------------------------------
__global__ __launch_bounds__(256) void mix4_kernel(
    const float* __restrict__ x,
    const float* __restrict__ mk, const float* __restrict__ mv,
    const float* __restrict__ mr,
    __bf16* __restrict__ xk, __bf16* __restrict__ xv, __bf16* __restrict__ xr) {
    const size_t idx = ((size_t)blockIdx.x * 256 + threadIdx.x) * 4;
    const int c = (int)(idx & (C_DIM - 1));
    const int t = (int)((idx >> 11) & (T_DIM - 1));   // C_DIM == 2^11

    f32x4 xc = *(const f32x4*)(x + idx);
    f32x4 sh = {0.f, 0.f, 0.f, 0.f};
    if (t != 0) sh = *(const f32x4*)(x + idx - C_DIM);
    f32x4 k4 = *(const f32x4*)(mk + c);
    f32x4 v4 = *(const f32x4*)(mv + c);
    f32x4 r4 = *(const f32x4*)(mr + c);

    bf16x4 ok, ov, orr;
#pragma unroll
    for (int j = 0; j < 4; ++j) {
        float xx = xc[j], ss = sh[j];
        ok[j]  = (__bf16)(xx * k4[j] + ss * (1.f - k4[j]));
        ov[j]  = (__bf16)(xx * v4[j] + ss * (1.f - v4[j]));
        orr[j] = (__bf16)(xx * r4[j] + ss * (1.f - r4[j]));
    }
    *(bf16x4*)(xk + idx) = ok;
    *(bf16x4*)(xv + idx) = ov;
    *(bf16x4*)(xr + idx) = orr;
}

// ---------------------------------------------------------------------------
// 256x256 bf16 GEMM, B^T input:  Cout[m][n] = sum_k A[m][k] * W[n][k]
// R5: R2's in-wave-pipelined kernel VERBATIM (best measured: 81.3-86.6 us,
// 0 bank conflicts) with ONE change: m-banded XCD mapping.  XCD x owns
// m_blks {4x..4x+3} x all 8 n_blks -> per-XCD unique footprint = 4 MB A-band
// (fits 4 MB L2, reused 8x) + 8 MB W, vs previous all-of-A per XCD
// (FETCH 135 MB -> expect ~96-105 MB).
// ---------------------------------------------------------------------------
#define LGKM(N)  do { asm volatile("s_waitcnt lgkmcnt(" #N ")" ::: "memory"); \
                      __builtin_amdgcn_sched_barrier(0); } while (0)
#define VM0()    asm volatile("s_waitcnt vmcnt(0)" ::: "memory")

#define MF1(mi, jj, AV, BV) \
    acc[mi][jj] = __builtin_amdgcn_mfma_f32_16x16x32_bf16(AV, BV, acc[mi][jj], 0, 0, 0)

#define MFMA16(MB, AA, BB)                                                        \
    __builtin_amdgcn_s_setprio(1);                                                \
    MF1(MB+0,0,AA[0],BB[0]); MF1(MB+0,1,AA[0],BB[1]);                             \
    MF1(MB+0,2,AA[0],BB[2]); MF1(MB+0,3,AA[0],BB[3]);                             \
    MF1(MB+1,0,AA[1],BB[0]); MF1(MB+1,1,AA[1],BB[1]);                             \
    MF1(MB+1,2,AA[1],BB[2]); MF1(MB+1,3,AA[1],BB[3]);                             \
    MF1(MB+2,0,AA[2],BB[0]); MF1(MB+2,1,AA[2],BB[1]);                             \
    MF1(MB+2,2,AA[2],BB[2]); MF1(MB+2,3,AA[2],BB[3]);                             \
    MF1(MB+3,0,AA[3],BB[0]); MF1(MB+3,1,AA[3],BB[1]);                             \
    MF1(MB+3,2,AA[3],BB[2]); MF1(MB+3,3,AA[3],BB[3]);                             \
    __builtin_amdgcn_s_setprio(0)

// stage one 64-K supertile (A and B, 256 rows x 64 k each): 8 gld_lds/thread.
#define STAGE8(KOF, BOE)                                                          \
    do {                                                                          \
        gld_lds16(Ag + (KOF),                       lA + (BOE));                  \
        gld_lds16(Bg + (KOF),                       lB + (BOE));                  \
        gld_lds16(Ag + (KOF) + (size_t)64*C_DIM,    lA + (BOE) + 4096);           \
        gld_lds16(Bg + (KOF) + (size_t)64*C_DIM,    lB + (BOE) + 4096);           \
        gld_lds16(Ag + (KOF) + (size_t)128*C_DIM,   lA + (BOE) + 8192);           \
        gld_lds16(Bg + (KOF) + (size_t)128*C_DIM,   lB + (BOE) + 8192);           \
        gld_lds16(Ag + (KOF) + (size_t)192*C_DIM,   lA + (BOE) + 12288);          \
        gld_lds16(Bg + (KOF) + (size_t)192*C_DIM,   lB + (BOE) + 12288);          \
    } while (0)

template <bool OUTF32>
__global__ __launch_bounds__(512, 2) void gemm256_bt(
    const __bf16* __restrict__ A, const __bf16* __restrict__ W,
    void* __restrict__ Cout) {
    __shared__ __align__(16) __bf16 sA[2 * 16384];   // 64 KB: 2 x [256][64]
    __shared__ __align__(16) __bf16 sB[2 * 16384];   // 64 KB

    const int tid  = threadIdx.x;
    const int lane = tid & 63;
    const int wave = tid >> 6;
    const int wr   = wave >> 2;        // 0..1 -> m offset wr*128
    const int wc   = wave & 3;         // 0..3 -> n offset wc*64

    // m-banded XCD mapping (bijective): xcd = bid&7 owns m_blks {4x..4x+3}
    // across all 8 n_blks -> per-XCD L2 footprint 4 MB A + 8 MB W.
    const int bid = blockIdx.x;
    const int xcd = bid & 7;
    const int loc = bid >> 3;          // 0..31
    const int m_blk = xcd * 4 + (loc & 3);
    const int n_blk = loc >> 2;        // 0..7
    const int row0 = m_blk * 256;
    const int col0 = n_blk * 256;

    // Staging source (inverse-swizzled global k-group so LDS DMA is linear):
    // linear LDS slot (row r = tid>>3, slot s' = tid&7) holds k-group
    // g = s' ^ (r&7).  Issue i advances rows by 64 (swizzle-invariant).
    const int srow = tid >> 3;
    const int sg   = (tid & 7) ^ (srow & 7);
    const __bf16* Ag = A + (size_t)(row0 + srow) * C_DIM + sg * 8;
    const __bf16* Bg = W + (size_t)(col0 + srow) * C_DIM + sg * 8;
    __bf16* lA = sA + wave * 512;      // + buf*16384 + issue*4096 (elements)
    __bf16* lB = sB + wave * 512;

    // Fragment read bases (elements).  Lane (row = R0 + l15, q = lane>>4)
    // reads k-group g = 4*ks + q at slot s' = g ^ (l15&7):
    //   elem = row*64 + s'*8;  ks=1 flips bit2 of s' -> XOR 32 elements.
    const int l15 = lane & 15;
    const int q   = lane >> 4;
    const int sw0 = (q ^ (l15 & 7)) * 8;
    const int aE0 = wr * 8192 + l15 * 64 + sw0;
    const int aE1 = aE0 ^ 32;
    const int bE0 = wc * 4096 + l15 * 64 + sw0;
    const int bE1 = bE0 ^ 32;

    f32x4  acc[8][4] = {};
    bf16x8 a0[4], a1[4], b0f[4], b1f[4];

    // ---- prologue: stage supertile 0 into buf0; preload phase-1 fragments.
    STAGE8(0, 0);
    VM0();
    __builtin_amdgcn_s_barrier();
#pragma unroll
    for (int i = 0; i < 4; ++i) a0[i]  = *(const bf16x8*)(sA + aE0 + i * 1024);
#pragma unroll
    for (int j = 0; j < 4; ++j) b0f[j] = *(const bf16x8*)(sB + bE0 + j * 1024);

    // ---- main loop: supertiles 0..30 (31 iters); supertile 31 peeled.
#pragma unroll 1
    for (int s = 0; s < 31; ++s) {
        const int boe  = (s & 1) << 14;      // current buf (elements)
        const int boe1 = boe ^ 16384;        // next buf

        // ph1 (mh0,ks0): prefetch a1 = A(mh1,ks0); stage s+1; MFMA.
#pragma unroll
        for (int i = 0; i < 4; ++i)
            a1[i] = *(const bf16x8*)(sA + boe + aE0 + 4096 + i * 1024);
        STAGE8((s + 1) * 64, boe1);
        LGKM(4);
        MFMA16(0, a0, b0f);

        // ph2 (mh1,ks0): prefetch a0 = A(mh0,ks1), b1f = B(ks1); MFMA.
#pragma unroll
        for (int i = 0; i < 4; ++i)
            a0[i]  = *(const bf16x8*)(sA + boe + aE1 + i * 1024);
#pragma unroll
        for (int j = 0; j < 4; ++j)
            b1f[j] = *(const bf16x8*)(sB + boe + bE1 + j * 1024);
        LGKM(8);
        MFMA16(4, a1, b0f);

        // ph3 (mh0,ks1): prefetch a1 = A(mh1,ks1); drain DMA; MFMA; mid-bar.
#pragma unroll
        for (int i = 0; i < 4; ++i)
            a1[i] = *(const bf16x8*)(sA + boe + aE1 + 4096 + i * 1024);
        VM0();
        LGKM(4);
        MFMA16(0, a0, b1f);
        __builtin_amdgcn_s_barrier();

        // ph4 (mh1,ks1): prefetch next supertile's ph1 frags from buf1; MFMA.
#pragma unroll
        for (int i = 0; i < 4; ++i)
            a0[i]  = *(const bf16x8*)(sA + boe1 + aE0 + i * 1024);
#pragma unroll
        for (int j = 0; j < 4; ++j)
            b0f[j] = *(const bf16x8*)(sB + boe1 + bE0 + j * 1024);
        LGKM(8);
        MFMA16(4, a1, b1f);
        __builtin_amdgcn_s_barrier();
    }

    // ---- peeled tail: supertile 31 (buf1), no staging, no barriers.
    {
        const int boe = 16384;
#pragma unroll
        for (int i = 0; i < 4; ++i)
            a1[i] = *(const bf16x8*)(sA + boe + aE0 + 4096 + i * 1024);
        LGKM(4);
        MFMA16(0, a0, b0f);
#pragma unroll
        for (int i = 0; i < 4; ++i)
            a0[i]  = *(const bf16x8*)(sA + boe + aE1 + i * 1024);
#pragma unroll
        for (int j = 0; j < 4; ++j)
            b1f[j] = *(const bf16x8*)(sB + boe + bE1 + j * 1024);
        LGKM(8);
        MFMA16(4, a1, b0f);
#pragma unroll
        for (int i = 0; i < 4; ++i)
            a1[i] = *(const bf16x8*)(sA + boe + aE1 + 4096 + i * 1024);
        LGKM(4);
        MFMA16(0, a0, b1f);
        LGKM(0);
        MFMA16(4, a1, b1f);
    }

    // Epilogue: D row = (lane>>4)*4 + reg, col = lane&15 (m89-verified).
    const int crow = (lane >> 4) * 4;
#pragma unroll
    for (int mf = 0; mf < 8; ++mf)
#pragma unroll
        for (int jf = 0; jf < 4; ++jf)
#pragma unroll
            for (int r = 0; r < 4; ++r) {
                const int row = row0 + wr * 128 + mf * 16 + crow + r;
                const int col = col0 + wc * 64 + jf * 16 + l15;
                if constexpr (OUTF32) {
                    ((float*)Cout)[(size_t)row * C_DIM + col] = acc[mf][jf][r];
                } else {
                    ((__bf16*)Cout)[(size_t)row * C_DIM + col] = (__bf16)acc[mf][jf][r];
                }
            }
}

// ---------------------------------------------------------------------------
// WKV segmented scan, VECTORIZED (Guideline 13 / m18: scalar bf16 loads run
// ~2.35 TB/s vs 4.89 vectorized).  Each thread owns 4 consecutive channels:
// all k/v/r loads are bf16x4 (8 B/lane), state and output stores vectorized.
// grid (C/1024, B, SEG) = (2,8,32) = 512 blocks (2/CU, 8 waves/CU).
// State layout [seg][b][c] fp32 unchanged -> pass2 untouched.
// ---------------------------------------------------------------------------
__global__ __launch_bounds__(256) void wkv_pass1(
    const __bf16* __restrict__ kbuf, const __bf16* __restrict__ vbuf,
    const float* __restrict__ td,
    float* __restrict__ st_num, float* __restrict__ st_den,
    float* __restrict__ st_m) {
    const int c0 = (blockIdx.x * 256 + threadIdx.x) * 4;
    const int b = blockIdx.y;
    const int s = blockIdx.z;
    const size_t base = (size_t)b * T_DIM * C_DIM + (size_t)s * SEGL * C_DIM + c0;

    f32x4 td4 = *(const f32x4*)(td + c0);
    float w[4], num[4], den[4], mx[4];
#pragma unroll
    for (int e = 0; e < 4; ++e) {
        w[e] = -__expf(td4[e]);
        num[e] = 0.f; den[e] = 0.f; mx[e] = -1e38f;
    }

    for (int t0 = 0; t0 < SEGL; t0 += 8) {
        bf16x4 kt[8], vt[8];
#pragma unroll
        for (int j = 0; j < 8; ++j) {
            const size_t idx = base + (size_t)(t0 + j) * C_DIM;
            kt[j] = *(const bf16x4*)(kbuf + idx);
            vt[j] = *(const bf16x4*)(vbuf + idx);
        }
#pragma unroll
        for (int j = 0; j < 8; ++j) {
#pragma unroll
            for (int e = 0; e < 4; ++e) {
                float kk = (float)kt[j][e], vv = (float)vt[j][e];
                float ms  = fmaxf(mx[e] + w[e], kk);
                float e1s = __expf(mx[e] + w[e] - ms);
                float e2s = __expf(kk - ms);
                num[e] = e1s * num[e] + e2s * vv;
                den[e] = e1s * den[e] + e2s;
                mx[e]  = ms;
            }
        }
    }
    const size_t sidx = (size_t)s * (B_DIM * C_DIM) + (size_t)b * C_DIM + c0;
    f32x4 n4, d4, m4;
#pragma unroll
    for (int e = 0; e < 4; ++e) { n4[e] = num[e]; d4[e] = den[e]; m4[e] = mx[e]; }
    *(f32x4*)(st_num + sidx) = n4;
    *(f32x4*)(st_den + sidx) = d4;
    *(f32x4*)(st_m   + sidx) = m4;
}

__global__ __launch_bounds__(256) void wkv_pass2(
    const float* __restrict__ td,
    float* __restrict__ st_num, float* __restrict__ st_den,
    float* __restrict__ st_m) {
    const int bc = blockIdx.x * 256 + threadIdx.x;   // b*C + c
    const int c  = bc & (C_DIM - 1);
    const float w = -__expf(td[c]);
    const float wL = w * SEGL;

    float num = 0.f, den = 0.f, mx = -1e38f;
    for (int s = 0; s < SEG; ++s) {
        const size_t sidx = (size_t)s * (B_DIM * C_DIM) + bc;
        float na = st_num[sidx], da = st_den[sidx], ma = st_m[sidx];
        // write incoming state for this segment (overwrite aggregate)
        st_num[sidx] = num; st_den[sidx] = den; st_m[sidx] = mx;
        // combine: state <- decay^L(state) + aggregate
        float md = mx + wL;
        float mc = fmaxf(md, ma);
        float e1 = __expf(md - mc);
        float e2 = __expf(ma - mc);
        num = e1 * num + e2 * na;
        den = e1 * den + e2 * da;
        mx  = mc;
    }
}

__global__ __launch_bounds__(256) void wkv_pass3(
    const __bf16* __restrict__ kbuf, const __bf16* __restrict__ vbuf,
    const __bf16* __restrict__ rbuf, const float* __restrict__ td,
    const float* __restrict__ tf,
    const float* __restrict__ st_num, const float* __restrict__ st_den,
    const float* __restrict__ st_m, __bf16* __restrict__ abuf) {
    const int c0 = (blockIdx.x * 256 + threadIdx.x) * 4;
    const int b = blockIdx.y;
    const int s = blockIdx.z;
    const size_t base = (size_t)b * T_DIM * C_DIM + (size_t)s * SEGL * C_DIM + c0;

    f32x4 td4 = *(const f32x4*)(td + c0);
    f32x4 tf4 = *(const f32x4*)(tf + c0);
    const size_t sidx = (size_t)s * (B_DIM * C_DIM) + (size_t)b * C_DIM + c0;
    f32x4 n4 = *(const f32x4*)(st_num + sidx);
    f32x4 d4 = *(const f32x4*)(st_den + sidx);
    f32x4 m4 = *(const f32x4*)(st_m + sidx);

    float w[4], u[4], num[4], den[4], mx[4];
#pragma unroll
    for (int e = 0; e < 4; ++e) {
        w[e] = -__expf(td4[e]);
        u[e] = tf4[e];
        num[e] = n4[e]; den[e] = d4[e]; mx[e] = m4[e];
    }

    for (int t0 = 0; t0 < SEGL; t0 += 8) {
        bf16x4 kt[8], vt[8], rt[8];
#pragma unroll
        for (int j = 0; j < 8; ++j) {
            const size_t idx = base + (size_t)(t0 + j) * C_DIM;
            kt[j] = *(const bf16x4*)(kbuf + idx);
            vt[j] = *(const bf16x4*)(vbuf + idx);
            rt[j] = *(const bf16x4*)(rbuf + idx);
        }
#pragma unroll
        for (int j = 0; j < 8; ++j) {
            bf16x4 o4;
#pragma unroll
            for (int e = 0; e < 4; ++e) {
                float kk = (float)kt[j][e], vv = (float)vt[j][e], rr = (float)rt[j][e];
                float mo  = fmaxf(mx[e], kk + u[e]);
                float e1  = __expf(mx[e] - mo);
                float e2  = __expf(kk + u[e] - mo);
                float out = (e1 * num[e] + e2 * vv) / (e1 * den[e] + e2);

                float ms  = fmaxf(mx[e] + w[e], kk);
                float e1s = __expf(mx[e] + w[e] - ms);
                float e2s = __expf(kk - ms);
                num[e] = e1s * num[e] + e2s * vv;
                den[e] = e1s * den[e] + e2s;
                mx[e]  = ms;

                float sr = 1.f / (1.f + __expf(-rr));
                o4[e] = (__bf16)(sr * out);
            }
            *(bf16x4*)(abuf + base + (size_t)(t0 + j) * C_DIM) = o4;
        }
    }
}

// ---------------------------------------------------------------------------
extern "C" void kernel_launch(void* const* d_in, const int* in_sizes, int n_in,
                              void* d_out, int out_size, void* d_ws, size_t ws_size,
                              hipStream_t stream) {
    (void)in_sizes; (void)n_in; (void)out_size; (void)ws_size;
    const float* x  = (const float*)d_in[0];
    const float* td = (const float*)d_in[1];
    const float* tf = (const float*)d_in[2];
    const float* mk = (const float*)d_in[3];
    const float* mv = (const float*)d_in[4];
    const float* mr = (const float*)d_in[5];
    const float* Wk = (const float*)d_in[6];
    const float* Wv = (const float*)d_in[7];
    const float* Wr = (const float*)d_in[8];
    const float* Wo = (const float*)d_in[9];
    float* out = (float*)d_out;

    const size_t WN = (size_t)C_DIM * C_DIM;    // 4,194,304
    const size_t n  = (size_t)M_DIM * C_DIM;    // 16,777,216

    // ws layout (bf16 elements): [Wk|Wv|Wr|Wo bf16][slot0][slot1][slot2][slot3]
    __bf16* Wb  = (__bf16*)d_ws;
    __bf16* Wkb = Wb;
    __bf16* Wvb = Wb + WN;
    __bf16* Wrb = Wb + 2 * WN;
    __bf16* Wob = Wb + 3 * WN;
    __bf16* xk  = Wb + 4 * WN;                  // slot 0
    __bf16* xv  = xk + n;                       // slot 1
    __bf16* xr  = xv + n;                       // slot 2
    __bf16* kb  = xr + n;                       // slot 3
    __bf16* vb  = xk;                           // reuse slot 0 (xk dead)
    __bf16* rb  = xv;                           // reuse slot 1 (xv dead)
    __bf16* ab  = xr;                           // reuse slot 2 (xr dead)

    // WKV state arrays (6.3 MB) live in the Wkb region: Wkb is dead once the
    // k-GEMM completes, and cast_w rewrites it at the start of every launch.
    float* st_num = (float*)d_ws;
    float* st_den = st_num + (size_t)SEG * B_DIM * C_DIM;
    float* st_m   = st_den + (size_t)SEG * B_DIM * C_DIM;

    cast_w_kernel<<<dim3((unsigned)(WN / 4 / 256), 4), 256, 0, stream>>>(
        Wk, Wv, Wr, Wo, Wb);

    mix4_kernel<<<dim3((unsigned)(n / 4 / 256)), 256, 0, stream>>>(
        x, mk, mv, mr, xk, xv, xr);

    dim3 ggrid((M_DIM / 256) * (C_DIM / 256));  // 32 x 8 = 256 blocks (1/CU)
    gemm256_bt<false><<<ggrid, 512, 0, stream>>>(xk, Wkb, kb);
    gemm256_bt<false><<<ggrid, 512, 0, stream>>>(xv, Wvb, vb);
    gemm256_bt<false><<<ggrid, 512, 0, stream>>>(xr, Wrb, rb);

    dim3 wgrid(C_DIM / 1024, B_DIM, SEG);       // 2 x 8 x 32 = 512 blocks
    wkv_pass1<<<wgrid, 256, 0, stream>>>(kb, vb, td, st_num, st_den, st_m);
    wkv_pass2<<<dim3(B_DIM * C_DIM / 256), 256, 0, stream>>>(
        td, st_num, st_den, st_m);
    wkv_pass3<<<wgrid, 256, 0, stream>>>(kb, vb, rb, td, tf,
                                         st_num, st_den, st_m, ab);

    gemm256_bt<true><<<ggrid, 512, 0, stream>>>(ab, Wob, out);
}